// Round 6
// baseline (757.330 us; speedup 1.0000x reference)
//
#include <hip/hip_runtime.h>
#include <cstdint>
#include <cstddef>

#define TT 1000
#define NB 64000  // B*T

// ---------------------------------------------------------------------------
// NUMERICS CONTRACT (r1/r5 verified absmax 0.0): each z[n,o] is ONE
// ascending-k fp32 add chain of W[o,k] over active k (spikes are 0/1, so
// fmaf(1,W,acc)==__fadd_rn(acc,W), fmaf(0,..)==identity). Sparse gather-add
// in ascending k order is BIT-IDENTICAL to the dense np BLAS chain.
// ---------------------------------------------------------------------------

// ---------------------------------------------------------------------------
// Sparse GEMM, O=256: Z[n][0:256] = sum over active k of Wt[k][0:256].
// Mask: per-n bitmask, mstride u64 words per row (word c covers k in
// [64c,64c+64), bit j = k 64c+j). Wt: [K][256] f32. KC = # of 64-k chunks.
// Block 1024 thr = 16 waves; wave owns 16 rows, lane covers o = lane*4..+3
// (ds_read_b128, conflict-free). W chunk staged in LDS (<=64 KB).
// ---------------------------------------------------------------------------
template <int KC>
__global__ __launch_bounds__(1024) void gemm_sp256(
    const unsigned long long* __restrict__ Mask, int mstride,
    const float* __restrict__ Wt, float* __restrict__ Z) {
  constexpr int KROWS = (KC == 1) ? 32 : 64;
  __shared__ __align__(16) float WL[KROWS * 256];
  const int t = threadIdx.x;
  const int lane = t & 63;
  const int wave = t >> 6;
  const int n0 = blockIdx.x * 256 + wave * 16;
  const int ox = lane * 4;

  float4 acc[16];
#pragma unroll
  for (int r = 0; r < 16; r++) acc[r] = make_float4(0.f, 0.f, 0.f, 0.f);

  for (int c = 0; c < KC; c++) {
    // stage chunk c (contiguous KROWS*256 floats), coalesced float4 copy
    const float* src = Wt + (size_t)c * KROWS * 256;
#pragma unroll
    for (int i = 0; i < (KROWS * 256) / 4096; i++) {
      int idx = i * 4096 + t * 4;
      *(float4*)&WL[idx] = *(const float4*)&src[idx];
    }
    __syncthreads();
    unsigned long long mnext = Mask[(size_t)n0 * mstride + c];
#pragma unroll
    for (int r = 0; r < 16; r++) {
      unsigned long long m = mnext;
      if (r < 15) mnext = Mask[(size_t)(n0 + r + 1) * mstride + c];
      while (m) {
        int k = __builtin_ctzll(m);  // ascending k within chunk
        m &= m - 1;
        const float4 w = *(const float4*)&WL[k * 256 + ox];
        acc[r].x = __fadd_rn(acc[r].x, w.x);
        acc[r].y = __fadd_rn(acc[r].y, w.y);
        acc[r].z = __fadd_rn(acc[r].z, w.z);
        acc[r].w = __fadd_rn(acc[r].w, w.w);
      }
    }
    __syncthreads();
  }
#pragma unroll
  for (int r = 0; r < 16; r++)
    *(float4*)&Z[(size_t)(n0 + r) * 256 + ox] = acc[r];
}

// ---------------------------------------------------------------------------
// Sparse GEMM, O=35 (layer 4). Wt4: [256][35] f32. Lane = o (lanes >=35
// idle-clamped). Same ascending-k chain; Z stride 35.
// ---------------------------------------------------------------------------
__global__ __launch_bounds__(1024) void gemm_sp35(
    const unsigned long long* __restrict__ Mask, const float* __restrict__ Wt,
    float* __restrict__ Z) {
  __shared__ float WL[64 * 35];
  const int t = threadIdx.x;
  const int lane = t & 63;
  const int wave = t >> 6;
  const int n0 = blockIdx.x * 256 + wave * 16;
  const int ol = lane < 35 ? lane : 34;
  float acc[16];
#pragma unroll
  for (int r = 0; r < 16; r++) acc[r] = 0.f;

  for (int c = 0; c < 4; c++) {
    const float* src = Wt + c * 64 * 35;
    for (int i = t; i < 64 * 35; i += 1024) WL[i] = src[i];
    __syncthreads();
    unsigned long long mnext = Mask[(size_t)n0 * 4 + c];
#pragma unroll
    for (int r = 0; r < 16; r++) {
      unsigned long long m = mnext;
      if (r < 15) mnext = Mask[(size_t)(n0 + r + 1) * 4 + c];
      while (m) {
        int k = __builtin_ctzll(m);
        m &= m - 1;
        acc[r] = __fadd_rn(acc[r], WL[k * 35 + ol]);
      }
    }
    __syncthreads();
  }
  if (lane < 35) {
#pragma unroll
    for (int r = 0; r < 16; r++) Z[(size_t)(n0 + r) * 35 + lane] = acc[r];
  }
}

// ---------------------------------------------------------------------------
// CUBA LIF recurrence: depth-4 x U=25 load pipeline; exact per-step fp32
// mul/add chain (unchanged). Non-final layers emit spike BITMASKS via
// __ballot: wave covers o in [o0,o0+64), stores u64 word (o0>>6) per t.
// ---------------------------------------------------------------------------
template <bool FINAL>
__global__ __launch_bounds__(64) void cuba_kernel(
    const float* __restrict__ Z, unsigned long long* __restrict__ Mout,
    float* __restrict__ Fout, unsigned int* __restrict__ cnt, int O,
    int total) {
  int gid = blockIdx.x * 64 + threadIdx.x;
  unsigned int c = 0;
  if (gid < total) {  // total % 64 == 0: whole wave uniform
    int b = gid / O;
    int o = gid - b * O;
    const int nb = b * TT;
    const float* zp = Z + (size_t)nb * O + o;
    float* fp = Fout + ((size_t)b * O + o) * TT;
    unsigned long long* mp = FINAL ? nullptr : Mout + ((o & ~63) >> 6);
    float cur = 0.f, volt = 0.f;
    constexpr int U = 25;  // 1000 = 40 batches, 4-deep pipeline
    float z0[U], z1[U], z2[U], z3[U];

#define LOADB(buf, tbase)                         \
  _Pragma("unroll") for (int u = 0; u < U; u++) { \
    buf[u] = zp[(size_t)((tbase) + u) * O];       \
  }
#define COMPB(buf, tbase)                                          \
  _Pragma("unroll") for (int u = 0; u < U; u++) {                  \
    cur = __fadd_rn(__fmul_rn(0.75f, cur), buf[u]);                \
    volt = __fadd_rn(__fmul_rn(0.97f, volt), cur);                 \
    bool fire = volt >= 1.25f;                                     \
    volt = fire ? 0.f : volt;                                      \
    c += fire ? 1u : 0u;                                           \
    if (FINAL) {                                                   \
      fp[(tbase) + u] = fire ? 1.f : 0.f;                          \
    } else {                                                       \
      unsigned long long mb = __ballot(fire);                      \
      if (threadIdx.x == 0)                                        \
        mp[(size_t)(nb + (tbase) + u) * 4] = mb;                   \
    }                                                              \
  }

    LOADB(z0, 0)
    LOADB(z1, U)
    LOADB(z2, 2 * U)
    for (int i = 0; i < 10; i++) {
      const int base = i * 4 * U;
      LOADB(z3, base + 3 * U)
      COMPB(z0, base)
      if (i < 9) LOADB(z0, base + 4 * U)
      COMPB(z1, base + U)
      if (i < 9) LOADB(z1, base + 5 * U)
      COMPB(z2, base + 2 * U)
      if (i < 9) LOADB(z2, base + 6 * U)
      COMPB(z3, base + 3 * U)
    }
#undef LOADB
#undef COMPB
  }
#pragma unroll
  for (int off = 32; off; off >>= 1) c += __shfl_down(c, off, 64);
  if ((threadIdx.x & 63) == 0) atomicAdd(cnt, c);
}

// ---------------------------------------------------------------------------
// Input: [B,20,T] f32 -> per-n u64 bitmask (bit k = channel k active)
// ---------------------------------------------------------------------------
__global__ __launch_bounds__(256) void prep_input(
    const float* __restrict__ X, unsigned long long* __restrict__ Mi) {
  int gid = blockIdx.x * 256 + threadIdx.x;
  if (gid >= NB) return;
  int b = gid / TT, tt = gid - b * TT;
  unsigned int w = 0;
#pragma unroll
  for (int c = 0; c < 20; c++) {
    float v = X[((size_t)b * 20 + c) * TT + tt];
    w |= (v != 0.f ? 1u : 0u) << c;
  }
  Mi[gid] = (unsigned long long)w;
}

// W [O,K] -> Wt [Kpad,Opad] transposed + zero-padded (value-exact copy)
__global__ __launch_bounds__(256) void prep_w(const float* __restrict__ W,
                                              float* __restrict__ Wt, int O,
                                              int K, int Kpad, int Opad) {
  int i = blockIdx.x * 256 + threadIdx.x;
  if (i >= Kpad * Opad) return;
  int k = i / Opad, o = i - k * Opad;
  Wt[i] = (k < K && o < O) ? W[(size_t)o * K + k] : 0.f;
}

__global__ void finalize_counts(const unsigned int* __restrict__ cnt,
                                float* __restrict__ out) {
  int i = threadIdx.x;
  if (i < 4) {
    const float denom[4] = {16384000.f, 16384000.f, 16384000.f, 2240000.f};
    out[i] = (float)cnt[i] / denom[i];
  }
}

// ---------------------------------------------------------------------------
extern "C" void kernel_launch(void* const* d_in, const int* in_sizes, int n_in,
                              void* d_out, int out_size, void* d_ws,
                              size_t ws_size, hipStream_t stream) {
  const float* X = (const float*)d_in[0];
  const float* W1 = (const float*)d_in[1];
  const float* W2 = (const float*)d_in[2];
  const float* W3 = (const float*)d_in[3];
  const float* W4 = (const float*)d_in[4];
  float* out = (float*)d_out;

  char* ws = (char*)d_ws;
  unsigned int* cnt = (unsigned int*)ws;  // 256 B
  float* Z = (float*)(ws + 256);          // 65,536,000 B
  unsigned long long* Mi =
      (unsigned long long*)(ws + 256 + 65536000ull);  // 512,000 B
  unsigned long long* Ma = Mi + 64000ull;             // 2,048,000 B
  unsigned long long* Mb = Ma + 256000ull;            // 2,048,000 B
  float* Wt1 = (float*)(Mb + 256000ull);              // 32*256*4
  float* Wt2 = Wt1 + 32 * 256;                        // 256*256*4
  float* Wt3 = Wt2 + 256 * 256;                       // 256*256*4
  float* Wt4 = Wt3 + 256 * 256;                       // 256*35*4

  hipMemsetAsync(cnt, 0, 16, stream);
  prep_w<<<(32 * 256 + 255) / 256, 256, 0, stream>>>(W1, Wt1, 256, 20, 32, 256);
  prep_w<<<(256 * 256) / 256, 256, 0, stream>>>(W2, Wt2, 256, 256, 256, 256);
  prep_w<<<(256 * 256) / 256, 256, 0, stream>>>(W3, Wt3, 256, 256, 256, 256);
  prep_w<<<(256 * 35 + 255) / 256, 256, 0, stream>>>(W4, Wt4, 35, 256, 256,
                                                     35);
  prep_input<<<(NB + 255) / 256, 256, 0, stream>>>(X, Mi);

  // layer 1 (K=32 padded, 1 chunk, mask stride 1)
  gemm_sp256<1><<<250, 1024, 0, stream>>>(Mi, 1, Wt1, Z);
  cuba_kernel<false><<<256, 64, 0, stream>>>(Z, Ma, nullptr, cnt + 0, 256,
                                             16384);
  // layer 2
  gemm_sp256<4><<<250, 1024, 0, stream>>>(Ma, 4, Wt2, Z);
  cuba_kernel<false><<<256, 64, 0, stream>>>(Z, Mb, nullptr, cnt + 1, 256,
                                             16384);
  // layer 3
  gemm_sp256<4><<<250, 1024, 0, stream>>>(Mb, 4, Wt3, Z);
  cuba_kernel<false><<<256, 64, 0, stream>>>(Z, Ma, nullptr, cnt + 2, 256,
                                             16384);
  // layer 4 (O=35)
  gemm_sp35<<<250, 1024, 0, stream>>>(Ma, Wt4, Z);
  cuba_kernel<true><<<35, 64, 0, stream>>>(Z, nullptr, out, cnt + 3, 35, 2240);
  finalize_counts<<<1, 64, 0, stream>>>(cnt, out + 2240000);
}